// Round 4
// baseline (334.452 us; speedup 1.0000x reference)
//
#include <hip/hip_runtime.h>
#include <cstdint>
#include <cstddef>

#define N_TOK   32768
#define DIM     1024
#define NE      64
#define KSPLIT  8
#define KPB     (DIM / KSPLIT)   // 128 k per block
#define ROWS_PB 512
#define CHK     16               // k per staged chunk
#define NCH     (KPB / CHK)      // 8 chunks

typedef __attribute__((ext_vector_type(16))) float f16v;
typedef const __attribute__((address_space(4))) f16v* cfp16;   // -> s_load_dwordx16

__device__ __forceinline__ void gload16(const float* g, float* l) {
  __builtin_amdgcn_global_load_lds(
      (const __attribute__((address_space(1))) uint32_t*)g,
      (__attribute__((address_space(3))) uint32_t*)l, 16, 0, 0);
}

// K1: partial GEMM. Block = 512 rows x 64 experts x one k-eighth.
// All 8 waves share ONE W s_load stream (same addresses -> sL1 hits).
// No __syncthreads in the K-loop: x tiles are wave-private, synced by vmcnt.
__global__ __launch_bounds__(512, 4) void k1_gemm(
    const float* __restrict__ x, const float* __restrict__ W,
    float* __restrict__ probs) {
  __shared__ float xs[16384];   // 64 KB: [2][512 rows][16 k]; buf1 reused for transpose

  const int tid  = threadIdx.x;
  const int lane = tid & 63;
  const int w    = __builtin_amdgcn_readfirstlane(tid >> 6);   // 0..7
  const int kq   = blockIdx.x & 7;
  const int rowbase = (blockIdx.x >> 3) * ROWS_PB;
  const int k0   = kq * KPB;

  // stage chunk c: 4 DMA instrs per wave, covering this wave's 64 rows.
  // phys quad slot (lane&3) holds logical quad q = (lane&3)^(row&3)  [bank swizzle]
  auto stage = [&](int c) {
    const int rsub = lane >> 2;                 // 0..15
    const int q    = (lane & 3) ^ (rsub & 3);
#pragma unroll
    for (int j = 0; j < 4; ++j) {
      const int srcRow = rowbase + w * 64 + 16 * j + rsub;
      gload16(x + (size_t)srcRow * DIM + k0 + c * CHK + q * 4,
              xs + (c & 1) * 8192 + (w * 4 + j) * 256);
    }
  };

  float acc[64];
#pragma unroll
  for (int e = 0; e < 64; ++e) acc[e] = 0.f;

  const int row_local = w * 64 + lane;
  stage(0);

#pragma unroll 1
  for (int c = 0; c < NCH; ++c) {
    if (c + 1 < NCH) {
      stage(c + 1);
      __asm__ __volatile__("" ::: "memory");
      __builtin_amdgcn_s_waitcnt(0x0F74);   // vmcnt(4): chunk c's DMAs done
      __asm__ __volatile__("" ::: "memory");
    } else {
      __asm__ __volatile__("" ::: "memory");
      __builtin_amdgcn_s_waitcnt(0x0F70);   // vmcnt(0)
      __asm__ __volatile__("" ::: "memory");
    }

    // this lane's 16 x-values into registers (undo quad swizzle)
    const float* xb = xs + (c & 1) * 8192 + row_local * 16;
    float4 xq[4];
#pragma unroll
    for (int q = 0; q < 4; ++q)
      xq[q] = *(const float4*)(xb + ((q ^ (lane & 3)) << 2));

    const size_t kbase = (size_t)(k0 + c * CHK) * NE;
#pragma unroll
    for (int kk = 0; kk < CHK; ++kk) {
      const float xc = ((const float*)&xq[kk >> 2])[kk & 3];
      cfp16 wp = (cfp16)(W + kbase + (size_t)kk * NE);
      const f16v wa = wp[0], wb = wp[1], wc = wp[2], wd = wp[3];
#pragma unroll
      for (int e = 0; e < 16; ++e) acc[e]      = fmaf(wa[e], xc, acc[e]);
#pragma unroll
      for (int e = 0; e < 16; ++e) acc[16 + e] = fmaf(wb[e], xc, acc[16 + e]);
#pragma unroll
      for (int e = 0; e < 16; ++e) acc[32 + e] = fmaf(wc[e], xc, acc[32 + e]);
#pragma unroll
      for (int e = 0; e < 16; ++e) acc[48 + e] = fmaf(wd[e], xc, acc[48 + e]);
    }
  }

  // ---- epilogue: per-wave LDS transpose (reuse buf1) + coalesced atomics ----
  // final logits = 0xAA-poison + sum of 8 k-partials; poison is a uniform
  // additive constant over ALL logits -> cancels in top-k & softmax (K2).
  float* tr = xs + 8192 + w * 1024;   // per-wave [16 rows][64 e], wave-private
#pragma unroll 1
  for (int s4 = 0; s4 < 4; ++s4) {
    if ((lane >> 4) == s4) {          // the 16 lanes owning rows s4*16..+16
      const int r16 = lane & 15;
#pragma unroll
      for (int q = 0; q < 16; ++q) {
        const int slot = q ^ (r16 & 3);
        *(float4*)(tr + r16 * 64 + (slot << 2)) =
            make_float4(acc[q * 4], acc[q * 4 + 1], acc[q * 4 + 2], acc[q * 4 + 3]);
      }
    }
    const int lq = lane >> 2;
#pragma unroll
    for (int j = 0; j < 16; ++j) {
      const float v = tr[j * 64 + ((lq ^ (j & 3)) << 2) + (lane & 3)];
      const int r = rowbase + w * 64 + s4 * 16 + j;
      atomicAdd(probs + (size_t)r * NE + lane, v);   // 256B-contiguous per instr
    }
  }
}

// K2: in-place finalize: bias + 64-lane butterfly top-2 + 2-way softmax + indices
__global__ __launch_bounds__(256, 4) void k2_final(
    const float* __restrict__ bias, float* __restrict__ probs,
    float* __restrict__ idxo) {
  const int lane = threadIdx.x & 63;
  const int w    = threadIdx.x >> 6;
  const int gw   = blockIdx.x * 4 + w;
  const float bl = bias[lane];

#pragma unroll 1
  for (int i = 0; i < 16; ++i) {
    const int row = gw * 16 + i;
    float v1 = probs[(size_t)row * NE + lane] + bl;   // + uniform poison const (cancels)
    int   j1 = lane;
    float v2 = -__builtin_inff();
    int   j2 = 100;
#pragma unroll
    for (int m = 32; m >= 1; m >>= 1) {
      float u1 = __shfl_xor(v1, m, 64);
      int   k1 = __shfl_xor(j1, m, 64);
      float u2 = __shfl_xor(v2, m, 64);
      int   k2 = __shfl_xor(j2, m, 64);
      bool firstWins = (u1 > v1) || (u1 == v1 && k1 < j1);
      if (firstWins) {
        bool u2b = (u2 > v1) || (u2 == v1 && k2 < j1);
        v2 = u2b ? u2 : v1; j2 = u2b ? k2 : j1;
        v1 = u1; j1 = k1;
      } else if ((u1 > v2) || (u1 == v2 && k1 < j2)) {
        v2 = u1; j2 = k1;
      }
    }
    const float e2 = __expf(v2 - v1);
    const float p1 = 1.0f / (1.0f + e2);
    const float p2 = e2 * p1;
    probs[(size_t)row * NE + lane] = (lane == j1) ? p1 : (lane == j2) ? p2 : 0.0f;
    if (lane == 0)
      *(float2*)(idxo + (size_t)row * 2) = make_float2((float)j1, (float)j2);
  }
}

extern "C" void kernel_launch(void* const* d_in, const int* in_sizes, int n_in,
                              void* d_out, int out_size, void* d_ws, size_t ws_size,
                              hipStream_t stream) {
  (void)in_sizes; (void)n_in; (void)out_size; (void)d_ws; (void)ws_size;
  const float* x = (const float*)d_in[0];
  const float* W = (const float*)d_in[1];
  const float* b = (const float*)d_in[2];
  float* out  = (float*)d_out;
  float* idxo = out + (size_t)N_TOK * NE;

  hipLaunchKernelGGL(k1_gemm, dim3(512), dim3(512), 0, stream, x, W, out);
  hipLaunchKernelGGL(k2_final, dim3(512), dim3(256), 0, stream, b, out, idxo);
}